// Round 8
// baseline (190.375 us; speedup 1.0000x reference)
//
#include <hip/hip_runtime.h>
#include <stdint.h>

#define T_SEQ 2048
#define NH 16
#define HD 64
#define M_DIM 4096      // B*T
#define K_DIM 1024      // C

typedef __attribute__((ext_vector_type(8))) short bf16x8;
typedef __attribute__((ext_vector_type(4))) short bf16x4;
typedef __attribute__((ext_vector_type(4))) float f32x4;
typedef __attribute__((ext_vector_type(4))) unsigned short u16x4;

__device__ __forceinline__ unsigned short f2bf(float f) {
  union { float f; uint32_t u; } x; x.f = f;
  uint32_t u = x.u;
  return (unsigned short)((u + 0x7fffu + ((u >> 16) & 1u)) >> 16);
}

__device__ __forceinline__ uint32_t cvtpk_bf16(float a, float b) {
  uint32_t r;
  asm("v_cvt_pk_bf16_f32 %0, %1, %2" : "=v"(r) : "v"(a), "v"(b));
  return r;
}

// 16x16x16 bf16 MFMA (A k-span = lg*4+j matches S-reg layout); D/C tied.
__device__ __forceinline__ f32x4 mfma16(bf16x4 a, bf16x4 b, f32x4 c) {
  asm("v_mfma_f32_16x16x16_bf16 %0, %1, %2, %0" : "+v"(c) : "v"(a), "v"(b));
  return c;
}

__device__ __forceinline__ float max3f(float a, float b, float c) {
  return fmaxf(fmaxf(a, b), c);   // clang fuses to v_max3_f32
}

#define GLOAD16(g, l) __builtin_amdgcn_global_load_lds( \
    (const __attribute__((address_space(1))) unsigned int*)(g), \
    (__attribute__((address_space(3))) unsigned int*)(l), 16, 0, 0)

// ---- fused preprocessing: x->bf16, w_attn->bf16^T, w_proj->bf16^T ----
__device__ __forceinline__ void do_convert(const float* __restrict__ src,
                                           unsigned short* __restrict__ dst, int bid) {
  int idx = (bid * 256 + threadIdx.x) * 4;
  f32x4 v = *(const f32x4*)(src + idx);
  u16x4 o;
  #pragma unroll
  for (int i = 0; i < 4; ++i) o[i] = f2bf(v[i]);
  *(u16x4*)(dst + idx) = o;
}

__device__ __forceinline__ void do_transpose(const float* __restrict__ src,
                                             unsigned short* __restrict__ dst,
                                             int R, int Cn, int bx, int by,
                                             float (*tile)[65]) {
  const int r0 = by * 64, c0 = bx * 64;
  const int t = threadIdx.x;
  const int rr = t >> 4;
  const int c4 = (t & 15) * 4;
  #pragma unroll
  for (int p = 0; p < 4; ++p) {
    f32x4 v = *(const f32x4*)(src + (size_t)(r0 + p * 16 + rr) * Cn + c0 + c4);
    #pragma unroll
    for (int i = 0; i < 4; ++i) tile[p * 16 + rr][c4 + i] = v[i];
  }
  __syncthreads();
  #pragma unroll
  for (int p = 0; p < 4; ++p) {
    const int cl = p * 16 + rr;
    u16x4 o;
    #pragma unroll
    for (int i = 0; i < 4; ++i) o[i] = f2bf(tile[c4 + i][cl]);
    *(u16x4*)(dst + (size_t)(c0 + cl) * R + r0 + c4) = o;
  }
}

__global__ __launch_bounds__(256) void prep_kernel(
    const float* __restrict__ x, unsigned short* __restrict__ xb,
    const float* __restrict__ w_attn, unsigned short* __restrict__ wqkvT,
    const float* __restrict__ w_proj, unsigned short* __restrict__ wprojT) {
  __shared__ float tile[64][65];
  const int b = blockIdx.x;
  if (b < 4096) {
    do_convert(x, xb, b);
  } else if (b < 4096 + 768) {
    const int bid = b - 4096;
    do_transpose(w_attn, wqkvT, 1024, 3072, bid % 48, bid / 48, tile);
  } else {
    const int bid = b - 4864;
    do_transpose(w_proj, wprojT, 1024, 1024, bid % 16, bid / 16, tile);
  }
}

// ---- 3-stage pipelined GEMM (depth-2 prefetch, counted vmcnt, raw barrier) ----
template <int MODE>
__global__ __launch_bounds__(256, 3) void gemm3_kernel(
    const unsigned short* __restrict__ A,
    const unsigned short* __restrict__ Bt,
    const float* __restrict__ bias,
    unsigned short* __restrict__ qout,
    unsigned short* __restrict__ kout,
    unsigned short* __restrict__ vTout,
    float* __restrict__ fout) {
  constexpr int NS = K_DIM / 32;
  constexpr int NWG = (MODE == 0) ? 768 : 256;
  constexpr int NBC = (MODE == 0) ? 24 : 8;
  __shared__ __align__(16) unsigned short As[3][128 * 32];
  __shared__ __align__(16) unsigned short Bs[3][128 * 32];
  const int t = threadIdx.x;
  const int w = t >> 6, l = t & 63;
  const int wr = w >> 1, wc = w & 1;
  const int lr = l & 15, lg = l >> 4;
  const int wg = (blockIdx.x & 7) * (NWG >> 3) + (blockIdx.x >> 3);
  const int bc = wg % NBC, br = wg / NBC;

  f32x4 acc[4][4];
  const f32x4 zf = {0.f, 0.f, 0.f, 0.f};
  #pragma unroll
  for (int i = 0; i < 4; ++i)
    #pragma unroll
    for (int j = 0; j < 4; ++j) acc[i][j] = zf;

  const unsigned short* Abase = A + (size_t)(br * 128) * K_DIM;
  const unsigned short* Bbase = Bt + (size_t)(bc * 128) * K_DIM;
  const int uA0 = t, uA1 = t + 256;
  const int uB0 = t, uB1 = t + 256;

  #define STAGE(ks, buf) do {                                                   \
    const int k0 = (ks) * 32;                                                   \
    unsigned short* as = &As[0][0] + (buf) * (128 * 32);                        \
    unsigned short* bs = &Bs[0][0] + (buf) * (128 * 32);                        \
    GLOAD16(Abase + (size_t)(uA0 >> 2) * K_DIM + k0 + (uA0 & 3) * 8, as + uA0 * 8); \
    GLOAD16(Abase + (size_t)(uA1 >> 2) * K_DIM + k0 + (uA1 & 3) * 8, as + uA1 * 8); \
    GLOAD16(Bbase + (size_t)(uB0 >> 2) * K_DIM + k0 + (uB0 & 3) * 8, bs + uB0 * 8); \
    GLOAD16(Bbase + (size_t)(uB1 >> 2) * K_DIM + k0 + (uB1 & 3) * 8, bs + uB1 * 8); \
  } while (0)

  #define COMPUTE(buf) do {                                                      \
    const unsigned short* as = &As[0][0] + (buf) * (128 * 32);                   \
    const unsigned short* bs = &Bs[0][0] + (buf) * (128 * 32);                   \
    bf16x8 af[4], bfv[4];                                                        \
    _Pragma("unroll")                                                            \
    for (int f = 0; f < 4; ++f) {                                                \
      af[f]  = *(const bf16x8*)(as + (wr * 64 + f * 16 + lr) * 32 + lg * 8);     \
      bfv[f] = *(const bf16x8*)(bs + (wc * 64 + f * 16 + lr) * 32 + lg * 8);     \
    }                                                                            \
    _Pragma("unroll")                                                            \
    for (int fr = 0; fr < 4; ++fr)                                               \
      _Pragma("unroll")                                                          \
      for (int fc = 0; fc < 4; ++fc)                                             \
        acc[fr][fc] = __builtin_amdgcn_mfma_f32_16x16x32_bf16(af[fr], bfv[fc],   \
                                                              acc[fr][fc], 0, 0, 0); \
  } while (0)

  STAGE(0, 0);
  STAGE(1, 1);
  int b_cur = 0;
  #pragma unroll 1
  for (int ks = 0; ks < NS; ++ks) {
    if (ks == NS - 1) {
      asm volatile("s_waitcnt vmcnt(0)" ::: "memory");
    } else {
      asm volatile("s_waitcnt vmcnt(4)" ::: "memory");
    }
    __builtin_amdgcn_sched_barrier(0);
    __builtin_amdgcn_s_barrier();
    if (ks + 2 < NS) {
      const int b_stg = (b_cur == 0) ? 2 : b_cur - 1;
      STAGE(ks + 2, b_stg);
    }
    COMPUTE(b_cur);
    b_cur = (b_cur == 2) ? 0 : b_cur + 1;
  }
  #undef STAGE
  #undef COMPUTE

  #pragma unroll
  for (int fr = 0; fr < 4; ++fr) {
    #pragma unroll
    for (int fc = 0; fc < 4; ++fc) {
      const int m0 = br * 128 + wr * 64 + fr * 16 + lg * 4;
      const int n  = bc * 128 + wc * 64 + fc * 16 + lr;
      if (MODE == 0) {
        const int which = n >> 10, rem = n & 1023;
        const int h = rem >> 6, d = rem & 63;
        const int b = m0 >> 11, tt0 = m0 & 2047;
        const int bh = b * NH + h;
        if (which == 2) {
          u16x4 pack;
          #pragma unroll
          for (int r = 0; r < 4; ++r) pack[r] = f2bf(acc[fr][fc][r] + bias[n]);
          *(u16x4*)(vTout + ((size_t)bh * HD + d) * T_SEQ + tt0) = pack;
        } else {
          unsigned short* o = (which == 0) ? qout : kout;
          const float sc = (which == 0) ? 0.18033688011112042f : 1.0f;  // 0.125*log2(e)
          #pragma unroll
          for (int r = 0; r < 4; ++r)
            o[((size_t)bh * T_SEQ + tt0 + r) * HD + d] = f2bf((acc[fr][fc][r] + bias[n]) * sc);
        }
      } else {
        #pragma unroll
        for (int r = 0; r < 4; ++r)
          fout[(size_t)(m0 + r) * 1024 + n] = acc[fr][fc][r] + bias[n];
      }
    }
  }
}

// ---- causal flash attention, v6: 32 q-rows/wave (dual 16-row groups) ----
// 512 blocks = (bh, 128-row q-tile). Complement pairing: each CU's two
// resident blocks sum to a constant 36 iterations. K/V frags loaded once,
// used by both q-groups -> 2x MFMA per barrier/LDS-read. Depth-2 counted
// vmcnt pipeline over 3 rotating buffers.
__global__ __launch_bounds__(256, 2) void flash_attn_kernel(
    const unsigned short* __restrict__ qg,
    const unsigned short* __restrict__ kg,
    const unsigned short* __restrict__ vTg,
    unsigned short* __restrict__ yg) {
  __shared__ __align__(16) unsigned short Ks[3][64 * 64];
  __shared__ __align__(16) unsigned short Vs[3][64 * 64];

  const int t = threadIdx.x;
  const int w = t >> 6, l = t & 63;
  const int lr = l & 15, lg = l >> 4;
  const int i = blockIdx.x;
  const int half = i >> 8, j = i & 255;
  const int bh = (j & 7) * 4 + ((j >> 3) & 3);   // 4 heads per XCD
  const int g = j >> 5;                          // 0..7
  const int qt = half ? g : (15 - g);            // complement pairing
  const int nt = 2 * qt + 2;
  const int qw = qt * 128 + w * 32;
  const int qrowA = qw + lr, qrowB = qw + 16 + lr;
  const int swz = lr & 7;

  const int srow0 = t >> 3;
  const int sch = t & 7;

  const size_t kgb = (size_t)bh * T_SEQ * HD;
  const size_t vgb = (size_t)bh * HD * T_SEQ;
  const f32x4 zf = {0.f, 0.f, 0.f, 0.f};

  const size_t qoffA = ((size_t)bh * T_SEQ + qw + lr) * HD + lg * 8;
  const bf16x8 qfA0 = *(const bf16x8*)(qg + qoffA);    // pre-scaled by 0.125*log2e
  const bf16x8 qfA1 = *(const bf16x8*)(qg + qoffA + 32);
  const bf16x8 qfB0 = *(const bf16x8*)(qg + qoffA + 16 * HD);
  const bf16x8 qfB1 = *(const bf16x8*)(qg + qoffA + 16 * HD + 32);

  f32x4 accA[4], accB[4];
  #pragma unroll
  for (int k = 0; k < 4; ++k) { accA[k] = zf; accB[k] = zf; }
  float mA = 0.f, mB = 0.f;
  float lA = 0.f, lB = 0.f;
  bool rescaled = false;

  #define FSTAGE(kvt, buf) do {                                                  \
    const size_t kof = kgb + (size_t)(kvt) * 64 * HD;                            \
    const size_t vof = vgb + (size_t)(kvt) * 64;                                 \
    _Pragma("unroll")                                                            \
    for (int sh = 0; sh < 2; ++sh) {                                             \
      const int row = sh * 32 + srow0;                                           \
      const int sc = (sch ^ (row & 7)) * 8;                                      \
      GLOAD16(kg + kof + (size_t)row * HD + sc, Ks[buf] + row * 64 + sch * 8);   \
      GLOAD16(vTg + vof + (size_t)row * T_SEQ + sc, Vs[buf] + row * 64 + sch * 8); \
    }                                                                            \
  } while (0)

  FSTAGE(0, 0);
  FSTAGE(1, 1);

  int cur = 0;
  #pragma unroll 1
  for (int it = 0; it < nt; ++it) {
    if (it == nt - 1) {
      asm volatile("s_waitcnt vmcnt(0)" ::: "memory");
    } else {
      asm volatile("s_waitcnt vmcnt(4)" ::: "memory");   // stage(it) landed
    }
    __builtin_amdgcn_sched_barrier(0);
    __builtin_amdgcn_s_barrier();
    if (it + 2 < nt) {
      const int b_stg = (cur == 0) ? 2 : cur - 1;        // (it+2)%3
      FSTAGE(it + 2, b_stg);
    }

    // QK^T (swapped): lane holds (q, tkv = kv0 + fc*16 + lg*4 + r) per group
    const int kv0 = it * 64;
    f32x4 sA[4], sB[4];
    __builtin_amdgcn_s_setprio(1);
    #pragma unroll
    for (int fc = 0; fc < 4; ++fc) {
      const unsigned short* kr = Ks[cur] + (fc * 16 + lr) * 64;
      const bf16x8 k0v = *(const bf16x8*)(kr + ((lg ^ swz) * 8));
      const bf16x8 k1v = *(const bf16x8*)(kr + (((lg + 4) ^ swz) * 8));
      f32x4 sv = zf;
      sv = __builtin_amdgcn_mfma_f32_16x16x32_bf16(k0v, qfA0, sv, 0, 0, 0);
      sv = __builtin_amdgcn_mfma_f32_16x16x32_bf16(k1v, qfA1, sv, 0, 0, 0);
      sA[fc] = sv;
      f32x4 sw = zf;
      sw = __builtin_amdgcn_mfma_f32_16x16x32_bf16(k0v, qfB0, sw, 0, 0, 0);
      sw = __builtin_amdgcn_mfma_f32_16x16x32_bf16(k1v, qfB1, sw, 0, 0, 0);
      sB[fc] = sw;
    }
    __builtin_amdgcn_s_setprio(0);

    if (it >= nt - 2) {           // causal mask: last two tiles only
      #pragma unroll
      for (int fc = 0; fc < 4; ++fc)
        #pragma unroll
        for (int r = 0; r < 4; ++r) {
          const int tkv = kv0 + fc * 16 + lg * 4 + r;
          if (tkv > qrowA) sA[fc][r] = -1e30f;
          if (tkv > qrowB) sB[fc][r] = -1e30f;
        }
    }

    // defer-max safety check (both groups share the trigger)
    float mtA = max3f(sA[0][0], sA[0][1], sA[0][2]);
    mtA = max3f(mtA, sA[0][3], sA[1][0]);
    mtA = max3f(mtA, sA[1][1], sA[1][2]);
    mtA = max3f(mtA, sA[1][3], sA[2][0]);
    mtA = max3f(mtA, sA[2][1], sA[2][2]);
    mtA = max3f(mtA, sA[2][3], sA[3][0]);
    mtA = max3f(mtA, sA[3][1], sA[3][2]);
    mtA = fmaxf(mtA, sA[3][3]);
    float mtB = max3f(sB[0][0], sB[0][1], sB[0][2]);
    mtB = max3f(mtB, sB[0][3], sB[1][0]);
    mtB = max3f(mtB, sB[1][1], sB[1][2]);
    mtB = max3f(mtB, sB[1][3], sB[2][0]);
    mtB = max3f(mtB, sB[2][1], sB[2][2]);
    mtB = max3f(mtB, sB[2][3], sB[3][0]);
    mtB = max3f(mtB, sB[3][1], sB[3][2]);
    mtB = fmaxf(mtB, sB[3][3]);
    if (__any(fmaxf(mtA - mA, mtB - mB) > 8.f)) {        // rare path
      float mrA = fmaxf(mtA, __shfl_xor(mtA, 16));
      mrA = fmaxf(mrA, __shfl_xor(mrA, 32));
      float mrB = fmaxf(mtB, __shfl_xor(mtB, 16));
      mrB = fmaxf(mrB, __shfl_xor(mrB, 32));
      const float mnA = fmaxf(mA, mrA), mnB = fmaxf(mB, mrB);
      const float facA = __builtin_amdgcn_exp2f(mA - mnA);
      const float facB = __builtin_amdgcn_exp2f(mB - mnB);
      lA *= facA; lB *= facB;
      float frsA[4], frsB[4];
      #pragma unroll
      for (int r = 0; r < 4; ++r) {
        frsA[r] = __shfl(facA, lg * 4 + r);
        frsB[r] = __shfl(facB, lg * 4 + r);
      }
      #pragma unroll
      for (int fd = 0; fd < 4; ++fd)
        #pragma unroll
        for (int r = 0; r < 4; ++r) {
          accA[fd][r] *= frsA[r];
          accB[fd][r] *= frsB[r];
        }
      mA = mnA; mB = mnB;
      rescaled = true;
    }

    // P = exp2(s [- m]); fast path skips subtracts (m == 0)
    union { uint32_t d[2]; bf16x4 v; } pkdA[4], pkdB[4];
    {
      float e[4][4];
      if (rescaled) {
        #pragma unroll
        for (int fc = 0; fc < 4; ++fc)
          #pragma unroll
          for (int r = 0; r < 4; ++r) e[fc][r] = __builtin_amdgcn_exp2f(sA[fc][r] - mA);
      } else {
        #pragma unroll
        for (int fc = 0; fc < 4; ++fc)
          #pragma unroll
          for (int r = 0; r < 4; ++r) e[fc][r] = __builtin_amdgcn_exp2f(sA[fc][r]);
      }
      #pragma unroll
      for (int fc = 0; fc < 4; ++fc) {
        pkdA[fc].d[0] = cvtpk_bf16(e[fc][0], e[fc][1]);
        pkdA[fc].d[1] = cvtpk_bf16(e[fc][2], e[fc][3]);
      }
      lA += (((e[0][0] + e[0][1]) + (e[0][2] + e[0][3])) +
             ((e[1][0] + e[1][1]) + (e[1][2] + e[1][3]))) +
            (((e[2][0] + e[2][1]) + (e[2][2] + e[2][3])) +
             ((e[3][0] + e[3][1]) + (e[3][2] + e[3][3])));
    }
    {
      float e[4][4];
      if (rescaled) {
        #pragma unroll
        for (int fc = 0; fc < 4; ++fc)
          #pragma unroll
          for (int r = 0; r < 4; ++r) e[fc][r] = __builtin_amdgcn_exp2f(sB[fc][r] - mB);
      } else {
        #pragma unroll
        for (int fc = 0; fc < 4; ++fc)
          #pragma unroll
          for (int r = 0; r < 4; ++r) e[fc][r] = __builtin_amdgcn_exp2f(sB[fc][r]);
      }
      #pragma unroll
      for (int fc = 0; fc < 4; ++fc) {
        pkdB[fc].d[0] = cvtpk_bf16(e[fc][0], e[fc][1]);
        pkdB[fc].d[1] = cvtpk_bf16(e[fc][2], e[fc][3]);
      }
      lB += (((e[0][0] + e[0][1]) + (e[0][2] + e[0][3])) +
             ((e[1][0] + e[1][1]) + (e[1][2] + e[1][3]))) +
            (((e[2][0] + e[2][1]) + (e[2][2] + e[2][3])) +
             ((e[3][0] + e[3][1]) + (e[3][2] + e[3][3])));
    }

    // PV: V-frags loaded once, feed both groups (2x16 mfma16)
    __builtin_amdgcn_s_setprio(1);
    #pragma unroll
    for (int fd = 0; fd < 4; ++fd) {
      const unsigned short* vr = Vs[cur] + (fd * 16 + lr) * 64;
      bf16x4 vf[4];
      #pragma unroll
      for (int fc = 0; fc < 4; ++fc) {
        const int ch = (fc * 2 + (lg >> 1)) ^ swz;
        vf[fc] = *(const bf16x4*)(vr + ch * 8 + (lg & 1) * 4);
      }
      f32x4 a = accA[fd], b = accB[fd];
      #pragma unroll
      for (int fc = 0; fc < 4; ++fc) {
        a = mfma16(pkdA[fc].v, vf[fc], a);
        b = mfma16(pkdB[fc].v, vf[fc], b);
      }
      accA[fd] = a; accB[fd] = b;
    }
    __builtin_amdgcn_s_setprio(0);
    cur = (cur == 2) ? 0 : cur + 1;
  }
  #undef FSTAGE

  float lsA = lA, lsB = lB;
  lsA += __shfl_xor(lsA, 16);
  lsA += __shfl_xor(lsA, 32);
  lsB += __shfl_xor(lsB, 16);
  lsB += __shfl_xor(lsB, 32);

  const int b = bh >> 4, h = bh & 15;
  #pragma unroll
  for (int r = 0; r < 4; ++r) {
    const float lvA = __shfl(lsA, lg * 4 + r);
    const float lvB = __shfl(lsB, lg * 4 + r);
    const float liA = 1.f / lvA, liB = 1.f / lvB;
    const int ttA = qw + lg * 4 + r;
    #pragma unroll
    for (int fd = 0; fd < 4; ++fd) {
      const int d = fd * 16 + lr;
      yg[(((size_t)b * T_SEQ + ttA) * NH + h) * HD + d] = f2bf(accA[fd][r] * liA);
      yg[(((size_t)b * T_SEQ + ttA + 16) * NH + h) * HD + d] = f2bf(accB[fd][r] * liB);
    }
  }
}

extern "C" void kernel_launch(void* const* d_in, const int* in_sizes, int n_in,
                              void* d_out, int out_size, void* d_ws, size_t ws_size,
                              hipStream_t stream) {
  (void)in_sizes; (void)n_in; (void)out_size; (void)ws_size;
  const float* x      = (const float*)d_in[0];
  const float* w_attn = (const float*)d_in[1];
  const float* b_attn = (const float*)d_in[2];
  const float* w_proj = (const float*)d_in[3];
  const float* b_proj = (const float*)d_in[4];
  float* out = (float*)d_out;

  char* ws = (char*)d_ws;
  unsigned short* xb     = (unsigned short*)(ws);                  // 8 MiB  [4096][1024]
  unsigned short* wqkvT  = (unsigned short*)(ws + (8ull  << 20));  // 6 MiB  [3072][1024]
  unsigned short* wprojT = (unsigned short*)(ws + (14ull << 20));  // 2 MiB  [1024][1024]
  unsigned short* qb     = (unsigned short*)(ws + (16ull << 20));  // 8 MiB  [BH][T][D]
  unsigned short* kb     = (unsigned short*)(ws + (24ull << 20));  // 8 MiB  [BH][T][D]
  unsigned short* vT     = (unsigned short*)(ws + (32ull << 20));  // 8 MiB  [BH][D][T]
  unsigned short* yb     = (unsigned short*)(ws + (40ull << 20));  // 8 MiB  [4096][1024]

  prep_kernel<<<5120, 256, 0, stream>>>(x, xb, w_attn, wqkvT, w_proj, wprojT);
  gemm3_kernel<0><<<768, 256, 0, stream>>>(xb, wqkvT, b_attn, qb, kb, vT, nullptr);
  flash_attn_kernel<<<512, 256, 0, stream>>>(qb, kb, vT, yb);
  gemm3_kernel<1><<<256, 256, 0, stream>>>(yb, wprojT, b_proj, nullptr, nullptr, nullptr, out);
}